// Round 20
// baseline (94.303 us; speedup 1.0000x reference)
//
#include <hip/hip_runtime.h>
#include <cmath>

#define S_   128
#define W_   64
#define D_   200
#define H_   50
#define OUT_ 5

// ---------------------------------------------------------------------------
// Kernel 1: one block per sentence (conv+pool commuted into the projection).
// ---------------------------------------------------------------------------
__global__ __launch_bounds__(256) void k_sent(
    const int* __restrict__ doc, const float* __restrict__ emb,
    const float* __restrict__ w_word, const float* __restrict__ b_word,
    const float* __restrict__ cw1, const float* __restrict__ cb1,
    const float* __restrict__ cw2, const float* __restrict__ cb2,
    const float* __restrict__ cw3, const float* __restrict__ cb3,
    const float* __restrict__ Wi, const float* __restrict__ bi,
    const float* __restrict__ Wf, const float* __restrict__ bf,
    const float* __restrict__ Wr, const float* __restrict__ br,
    float* __restrict__ Xout)   // [3][S_][H_]
{
    const int s   = blockIdx.x;
    const int tid = threadIdx.x;

    __shared__ int   drow[W_];
    __shared__ float vec[5][D_];     // full sum, E0, E1, E62, E63
    __shared__ float q[5][H_];       // w_word @ each of the above
    __shared__ float m[6][H_ + 2];   // the 6 window means
    __shared__ float reps_sh[H_];

    if (tid < W_) drow[tid] = doc[s * W_ + tid];
    __syncthreads();

    if (tid < D_) {
        const int d = tid;
        float acc = 0.f;
        for (int u = 0; u < W_; ++u)
            acc += emb[(size_t)drow[u] * D_ + d];
        vec[0][d] = acc;
        vec[1][d] = emb[(size_t)drow[0]      * D_ + d];
        vec[2][d] = emb[(size_t)drow[1]      * D_ + d];
        vec[3][d] = emb[(size_t)drow[W_ - 2] * D_ + d];
        vec[4][d] = emb[(size_t)drow[W_ - 1] * D_ + d];
    }
    __syncthreads();

    if (tid < 5 * H_) {
        const int v = tid / H_, h = tid % H_;
        const float* wr = w_word + h * D_;
        float acc = 0.f;
        for (int d = 0; d < D_; ++d) acc += wr[d] * vec[v][d];
        q[v][h] = acc;
    }
    __syncthreads();

    if (tid < H_) {
        const int h = tid;
        const float qf = q[0][h], q0 = q[1][h], q1 = q[2][h],
                    q62 = q[3][h], q63 = q[4][h];
        const float bw = b_word[h];
        m[0][h] = qf               * (1.f / 64.f) + bw;
        m[1][h] = (qf - q63)       * (1.f / 63.f) + bw;
        m[2][h] = (qf - q0)        * (1.f / 63.f) + bw;
        m[3][h] = (qf - q62 - q63) * (1.f / 62.f) + bw;
        m[4][h] = (qf - q0  - q63) * (1.f / 62.f) + bw;
        m[5][h] = (qf - q0  - q1)  * (1.f / 62.f) + bw;
    }
    __syncthreads();

    if (tid < H_) {
        const int o = tid;
        float a1 = cb1[o], a2 = cb2[o], a3 = cb3[o];
        for (int i = 0; i < H_; ++i) {
            a1 += cw1[o * H_ + i] * m[0][i];
            const float* c2 = cw2 + (o * H_ + i) * 2;
            a2 += c2[0] * m[1][i] + c2[1] * m[2][i];
            const float* c3 = cw3 + (o * H_ + i) * 3;
            a3 += c3[0] * m[3][i] + c3[1] * m[4][i] + c3[2] * m[5][i];
        }
        reps_sh[o] = (tanhf(a1) + tanhf(a2) + tanhf(a3)) * (1.f / 3.f);
    }
    __syncthreads();

    if (tid < 3 * H_) {
        const int g = tid / H_, o = tid % H_;
        const float* Wg = (g == 0) ? Wi : (g == 1) ? Wf : Wr;
        const float* bg = (g == 0) ? bi : (g == 1) ? bf : br;
        float acc = bg[o];
        for (int j = 0; j < H_; ++j) acc += Wg[o * H_ + j] * reps_sh[j];
        Xout[(g * S_ + s) * H_ + o] = acc;
    }
}

// ---------------------------------------------------------------------------
// Kernel 2 (v9b): SINGLE-wave scan, zero barriers / zero LDS.
// Evidence: every 4-wave barrier-per-step variant costs 63-69us no matter
// what else is fixed (v6 63, v7 65, v8 69 with U resident AND 0 bank
// conflicts) -> the ds_write/barrier/ds_read exchange IS the critical path
// (~800cyc/step). Remove it: one wave holds ALL 50 columns as f16 pairs in
// 75 asm-fenced u32 regs (fence = def, no remat; v8 proved the technique),
// contracted with v_dot2_f32_f16 (2 MACs/instr, f32 accum).
// v9 compile fix: cvt_pkrtz returns __fp16x2, fdot2 wants _Float16x2 --
// route all packs through union bitcasts (decltype-matched), no implicit
// vector conversions anywhere.
// ---------------------------------------------------------------------------
typedef _Float16 f16x2 __attribute__((ext_vector_type(2)));
typedef decltype(__builtin_amdgcn_cvt_pkrtz(0.f, 0.f)) pk_t;

__device__ __forceinline__ unsigned int pkrtz(float a, float b) {
    union { pk_t h; unsigned int u; } c;
    c.h = __builtin_amdgcn_cvt_pkrtz(a, b);
    return c.u;
}
__device__ __forceinline__ f16x2 u2h(unsigned int u) {
    union { unsigned int u; f16x2 h; } c;
    c.u = u;
    return c.h;
}

__device__ __forceinline__ float tanh_fast(float x) {
    float e = __expf(2.f * x);
    return (e - 1.f) / (e + 1.f);
}

__device__ __forceinline__ float bcast(float v, int lane) {
    return __int_as_float(__builtin_amdgcn_readlane(__float_as_int(v), lane));
}

__global__ __launch_bounds__(64)
__attribute__((amdgpu_waves_per_eu(1, 1)))
void k_scan(
    const float* __restrict__ X,   // [3][S_][H_]
    const float* __restrict__ Ui, const float* __restrict__ Uf,
    const float* __restrict__ Ur,
    const float* __restrict__ Wout, const float* __restrict__ bout,
    float* __restrict__ out)
{
    const int o  = threadIdx.x & 63;
    const int ro = (o < H_) ? o : (H_ - 1);   // clamped: all lanes in-bounds

    // ---- load + pack ALL 50 columns of this row as f16 pairs (75 regs) ----
    unsigned int ua[H_ / 2], ub[H_ / 2], uc[H_ / 2];
    {
        const float* Uir = Ui + ro * H_;
        const float* Ufr = Uf + ro * H_;
        const float* Urr = Ur + ro * H_;
        #pragma unroll
        for (int k = 0; k < H_ / 2; ++k) {
            ua[k] = pkrtz(Uir[2 * k], Uir[2 * k + 1]);
            ub[k] = pkrtz(Ufr[2 * k], Ufr[2 * k + 1]);
            uc[k] = pkrtz(Urr[2 * k], Urr[2 * k + 1]);
        }
        // fence: asm becomes the def -> rematerialization impossible (v8)
        #pragma unroll
        for (int k = 0; k < H_ / 2; ++k) {
            asm volatile("" : "+v"(ua[k]));
            asm volatile("" : "+v"(ub[k]));
            asm volatile("" : "+v"(uc[k]));
        }
    }

    float h  = 0.f;                            // lane o owns h[o]
    float xi = X[(0 * S_ + 0) * H_ + ro];
    float xf = X[(1 * S_ + 0) * H_ + ro];
    float xr = X[(2 * S_ + 0) * H_ + ro];

    for (int t = 0; t < S_; ++t) {
        const int tn = (t + 1 < S_) ? (t + 1) : (S_ - 1);   // clamped prefetch
        float nxi = X[(0 * S_ + tn) * H_ + ro];
        float nxf = X[(1 * S_ + tn) * H_ + ro];
        float nxr = X[(2 * S_ + tn) * H_ + ro];

        float ai = xi, af = xf, ar = xr;
        #pragma unroll
        for (int k = 0; k < H_ / 2; ++k) {
            const float h0 = bcast(h, 2 * k);
            const float h1 = bcast(h, 2 * k + 1);
            const f16x2 hp = u2h(pkrtz(h0, h1));
            ai = __builtin_amdgcn_fdot2(u2h(ua[k]), hp, ai, false);
            af = __builtin_amdgcn_fdot2(u2h(ub[k]), hp, af, false);
            ar = __builtin_amdgcn_fdot2(u2h(uc[k]), hp, ar, false);
        }
        float gi = 1.f / (1.f + __expf(-ai));
        float gf = 1.f / (1.f + __expf(-af));
        float gg = tanh_fast(ar);
        h = tanh_fast(gi * gg + gf * h);
        xi = nxi; xf = nxf; xr = nxr;
    }

    // output head: logits in lanes 0..4, softmax redundantly in-wave (f32)
    float logit = (o < OUT_) ? bout[o] : 0.f;
    const float* wrow = Wout + ((o < OUT_) ? o : 0) * H_;
    #pragma unroll
    for (int j = 0; j < H_; ++j) {
        float hj = bcast(h, j);
        logit += wrow[j] * hj;
    }
    float l0 = bcast(logit, 0), l1 = bcast(logit, 1), l2 = bcast(logit, 2),
          l3 = bcast(logit, 3), l4 = bcast(logit, 4);
    float mx = fmaxf(fmaxf(fmaxf(l0, l1), fmaxf(l2, l3)), l4);
    float e0 = __expf(l0 - mx), e1 = __expf(l1 - mx), e2 = __expf(l2 - mx),
          e3 = __expf(l3 - mx), e4 = __expf(l4 - mx);
    float s = e0 + e1 + e2 + e3 + e4;
    if (o == 0) {
        out[0] = e0 / s; out[1] = e1 / s; out[2] = e2 / s;
        out[3] = e3 / s; out[4] = e4 / s;
    }
}

extern "C" void kernel_launch(void* const* d_in, const int* in_sizes, int n_in,
                              void* d_out, int out_size, void* d_ws, size_t ws_size,
                              hipStream_t stream) {
    (void)in_sizes; (void)n_in; (void)out_size; (void)ws_size;

    const int*   doc    = (const int*)  d_in[0];
    const float* emb    = (const float*)d_in[1];
    const float* w_word = (const float*)d_in[2];
    const float* b_word = (const float*)d_in[3];
    const float* cw1    = (const float*)d_in[4];
    const float* cb1    = (const float*)d_in[5];
    const float* cw2    = (const float*)d_in[6];
    const float* cb2    = (const float*)d_in[7];
    const float* cw3    = (const float*)d_in[8];
    const float* cb3    = (const float*)d_in[9];
    const float* Wi     = (const float*)d_in[10];
    const float* Ui     = (const float*)d_in[11];
    const float* bi     = (const float*)d_in[12];
    const float* Wf     = (const float*)d_in[13];
    const float* Uf     = (const float*)d_in[14];
    const float* bf     = (const float*)d_in[15];
    const float* Wr     = (const float*)d_in[16];
    const float* Ur     = (const float*)d_in[17];
    const float* br     = (const float*)d_in[18];
    const float* Wout   = (const float*)d_in[19];
    const float* bout   = (const float*)d_in[20];

    float* X = (float*)d_ws;                 // [3][S_][H_] f32 = 76.8 KB
    float* out = (float*)d_out;

    k_sent<<<S_, 256, 0, stream>>>(doc, emb, w_word, b_word,
                                   cw1, cb1, cw2, cb2, cw3, cb3,
                                   Wi, bi, Wf, bf, Wr, br, X);
    k_scan<<<1, 64, 0, stream>>>(X, Ui, Uf, Ur, Wout, bout, out);
}

// Round 21
// 71.955 us; speedup vs baseline: 1.3106x; 1.3106x over previous
//
#include <hip/hip_runtime.h>
#include <cmath>

#define S_   128
#define W_   64
#define D_   200
#define H_   50
#define OUT_ 5

// ---------------------------------------------------------------------------
// Kernel 1: one block per sentence (conv+pool commuted into the projection).
// ---------------------------------------------------------------------------
__global__ __launch_bounds__(256) void k_sent(
    const int* __restrict__ doc, const float* __restrict__ emb,
    const float* __restrict__ w_word, const float* __restrict__ b_word,
    const float* __restrict__ cw1, const float* __restrict__ cb1,
    const float* __restrict__ cw2, const float* __restrict__ cb2,
    const float* __restrict__ cw3, const float* __restrict__ cb3,
    const float* __restrict__ Wi, const float* __restrict__ bi,
    const float* __restrict__ Wf, const float* __restrict__ bf,
    const float* __restrict__ Wr, const float* __restrict__ br,
    float* __restrict__ Xout)   // [3][S_][H_]
{
    const int s   = blockIdx.x;
    const int tid = threadIdx.x;

    __shared__ int   drow[W_];
    __shared__ float vec[5][D_];     // full sum, E0, E1, E62, E63
    __shared__ float q[5][H_];       // w_word @ each of the above
    __shared__ float m[6][H_ + 2];   // the 6 window means
    __shared__ float reps_sh[H_];

    if (tid < W_) drow[tid] = doc[s * W_ + tid];
    __syncthreads();

    if (tid < D_) {
        const int d = tid;
        float acc = 0.f;
        for (int u = 0; u < W_; ++u)
            acc += emb[(size_t)drow[u] * D_ + d];
        vec[0][d] = acc;
        vec[1][d] = emb[(size_t)drow[0]      * D_ + d];
        vec[2][d] = emb[(size_t)drow[1]      * D_ + d];
        vec[3][d] = emb[(size_t)drow[W_ - 2] * D_ + d];
        vec[4][d] = emb[(size_t)drow[W_ - 1] * D_ + d];
    }
    __syncthreads();

    if (tid < 5 * H_) {
        const int v = tid / H_, h = tid % H_;
        const float* wr = w_word + h * D_;
        float acc = 0.f;
        for (int d = 0; d < D_; ++d) acc += wr[d] * vec[v][d];
        q[v][h] = acc;
    }
    __syncthreads();

    if (tid < H_) {
        const int h = tid;
        const float qf = q[0][h], q0 = q[1][h], q1 = q[2][h],
                    q62 = q[3][h], q63 = q[4][h];
        const float bw = b_word[h];
        m[0][h] = qf               * (1.f / 64.f) + bw;
        m[1][h] = (qf - q63)       * (1.f / 63.f) + bw;
        m[2][h] = (qf - q0)        * (1.f / 63.f) + bw;
        m[3][h] = (qf - q62 - q63) * (1.f / 62.f) + bw;
        m[4][h] = (qf - q0  - q63) * (1.f / 62.f) + bw;
        m[5][h] = (qf - q0  - q1)  * (1.f / 62.f) + bw;
    }
    __syncthreads();

    if (tid < H_) {
        const int o = tid;
        float a1 = cb1[o], a2 = cb2[o], a3 = cb3[o];
        for (int i = 0; i < H_; ++i) {
            a1 += cw1[o * H_ + i] * m[0][i];
            const float* c2 = cw2 + (o * H_ + i) * 2;
            a2 += c2[0] * m[1][i] + c2[1] * m[2][i];
            const float* c3 = cw3 + (o * H_ + i) * 3;
            a3 += c3[0] * m[3][i] + c3[1] * m[4][i] + c3[2] * m[5][i];
        }
        reps_sh[o] = (tanhf(a1) + tanhf(a2) + tanhf(a3)) * (1.f / 3.f);
    }
    __syncthreads();

    if (tid < 3 * H_) {
        const int g = tid / H_, o = tid % H_;
        const float* Wg = (g == 0) ? Wi : (g == 1) ? Wf : Wr;
        const float* bg = (g == 0) ? bi : (g == 1) ? bf : br;
        float acc = bg[o];
        for (int j = 0; j < H_; ++j) acc += Wg[o * H_ + j] * reps_sh[j];
        Xout[(g * S_ + s) * H_ + o] = acc;
    }
}

// ---------------------------------------------------------------------------
// Kernel 2 (v10): v6's 4-wave column-split structure (the measured champion,
// 63us; single-wave variants measured 78-88us) with the gate chain de-fanged:
// the four IEEE f32 divisions (2 sigmoids + 2 tanh) each cost ~60-80 cyc of
// dependent div_scale/div_fmas/div_fixup sequence ON the serial h-chain,
// every step, in every wave. Replace with v_rcp_f32 (~1e-7 rel err): each
// becomes exp->add->rcp->mul (~15 cyc). Exchange uses v8's [64][5] padding
// (measured 0 bank conflicts vs v6's 9216). U loads stay plain f32 (v6's
// fastest-measured dot path; residency proven irrelevant in v8).
// ---------------------------------------------------------------------------
#define JW 13   // columns per wave (4*13 = 52 >= 50; tail guarded)

__device__ __forceinline__ float rcp_fast(float x) {
    return __builtin_amdgcn_rcpf(x);
}

__device__ __forceinline__ float tanh_fast(float x) {
    float e = __expf(2.f * x);
    return (e - 1.f) * rcp_fast(e + 1.f);
}

__device__ __forceinline__ float sigmoid_fast(float x) {
    return rcp_fast(1.f + __expf(-x));
}

__device__ __forceinline__ float bcast(float v, int lane) {
    return __int_as_float(__builtin_amdgcn_readlane(__float_as_int(v), lane));
}

__global__ __launch_bounds__(256, 1) void k_scan(
    const float* __restrict__ X,   // [3][S_][H_]
    const float* __restrict__ Ui, const float* __restrict__ Uf,
    const float* __restrict__ Ur,
    const float* __restrict__ Wout, const float* __restrict__ bout,
    float* __restrict__ out)
{
    const int tid = threadIdx.x;
    const int w   = tid >> 6;                 // wave: 0..3
    const int o   = tid & 63;
    const int ro  = (o < H_) ? o : (H_ - 1);  // clamped row, all lanes in-bounds
    const int jlo = w * JW;                   // this wave's column window

    // part[parity][gate][o][wave(+pad)]: stride 5 -> conflict-free (v8: 0)
    __shared__ float part[2][3][64][5];

    float ua[JW], ub[JW], uc[JW];
    {
        const float* Uir = Ui + ro * H_;
        const float* Ufr = Uf + ro * H_;
        const float* Urr = Ur + ro * H_;
        #pragma unroll
        for (int jj = 0; jj < JW; ++jj) {
            const int j = jlo + jj;
            const bool ok = (j < H_);
            ua[jj] = ok ? Uir[j] : 0.f;
            ub[jj] = ok ? Ufr[j] : 0.f;
            uc[jj] = ok ? Urr[j] : 0.f;
        }
    }

    float h  = 0.f;                            // lane o holds h[o] (all waves)
    float xi = X[(0 * S_ + 0) * H_ + ro];
    float xf = X[(1 * S_ + 0) * H_ + ro];
    float xr = X[(2 * S_ + 0) * H_ + ro];

    int p = 0;
    for (int t = 0; t < S_; ++t) {
        const int tn = (t + 1 < S_) ? (t + 1) : (S_ - 1);   // clamped prefetch
        float nxi = X[(0 * S_ + tn) * H_ + ro];
        float nxf = X[(1 * S_ + tn) * H_ + ro];
        float nxr = X[(2 * S_ + tn) * H_ + ro];

        // partial dots over this wave's column window
        float pi = 0.f, pf = 0.f, pr = 0.f;
        #pragma unroll
        for (int jj = 0; jj < JW; ++jj) {
            const int j  = jlo + jj;
            const int jl = (j < H_) ? j : (H_ - 1);  // wave-uniform SGPR index
            float hj = bcast(h, jl);                 // garbage*0 stays finite
            pi += ua[jj] * hj;
            pf += ub[jj] * hj;
            pr += uc[jj] * hj;
        }
        part[p][0][o][w] = pi;
        part[p][1][o][w] = pf;
        part[p][2][o][w] = pr;
        __syncthreads();

        float ai = xi + (part[p][0][o][0] + part[p][0][o][1])
                      + (part[p][0][o][2] + part[p][0][o][3]);
        float af = xf + (part[p][1][o][0] + part[p][1][o][1])
                      + (part[p][1][o][2] + part[p][1][o][3]);
        float ar = xr + (part[p][2][o][0] + part[p][2][o][1])
                      + (part[p][2][o][2] + part[p][2][o][3]);

        float gi = sigmoid_fast(ai);
        float gf = sigmoid_fast(af);
        float gg = tanh_fast(ar);
        h = tanh_fast(gi * gg + gf * h);       // identical in all waves

        xi = nxi; xf = nxf; xr = nxr;
        p ^= 1;                                // double buffer: no 2nd barrier
    }

    // output head (all waves compute identically; tid 0 stores)
    float logit = (o < OUT_) ? bout[o] : 0.f;
    const float* wrow = Wout + ((o < OUT_) ? o : 0) * H_;
    #pragma unroll
    for (int j = 0; j < H_; ++j) {
        float hj = bcast(h, j);
        logit += wrow[j] * hj;
    }
    float l0 = bcast(logit, 0), l1 = bcast(logit, 1), l2 = bcast(logit, 2),
          l3 = bcast(logit, 3), l4 = bcast(logit, 4);
    float mx = fmaxf(fmaxf(fmaxf(l0, l1), fmaxf(l2, l3)), l4);
    float e0 = __expf(l0 - mx), e1 = __expf(l1 - mx), e2 = __expf(l2 - mx),
          e3 = __expf(l3 - mx), e4 = __expf(l4 - mx);
    float s = e0 + e1 + e2 + e3 + e4;
    if (tid == 0) {
        float rs = 1.f / s;   // one IEEE div in the epilogue is fine
        out[0] = e0 * rs; out[1] = e1 * rs; out[2] = e2 * rs;
        out[3] = e3 * rs; out[4] = e4 * rs;
    }
}

extern "C" void kernel_launch(void* const* d_in, const int* in_sizes, int n_in,
                              void* d_out, int out_size, void* d_ws, size_t ws_size,
                              hipStream_t stream) {
    (void)in_sizes; (void)n_in; (void)out_size; (void)ws_size;

    const int*   doc    = (const int*)  d_in[0];
    const float* emb    = (const float*)d_in[1];
    const float* w_word = (const float*)d_in[2];
    const float* b_word = (const float*)d_in[3];
    const float* cw1    = (const float*)d_in[4];
    const float* cb1    = (const float*)d_in[5];
    const float* cw2    = (const float*)d_in[6];
    const float* cb2    = (const float*)d_in[7];
    const float* cw3    = (const float*)d_in[8];
    const float* cb3    = (const float*)d_in[9];
    const float* Wi     = (const float*)d_in[10];
    const float* Ui     = (const float*)d_in[11];
    const float* bi     = (const float*)d_in[12];
    const float* Wf     = (const float*)d_in[13];
    const float* Uf     = (const float*)d_in[14];
    const float* bf     = (const float*)d_in[15];
    const float* Wr     = (const float*)d_in[16];
    const float* Ur     = (const float*)d_in[17];
    const float* br     = (const float*)d_in[18];
    const float* Wout   = (const float*)d_in[19];
    const float* bout   = (const float*)d_in[20];

    float* X = (float*)d_ws;                 // [3][S_][H_] f32 = 76.8 KB
    float* out = (float*)d_out;

    k_sent<<<S_, 256, 0, stream>>>(doc, emb, w_word, b_word,
                                   cw1, cb1, cw2, cb2, cw3, cb3,
                                   Wi, bi, Wf, bf, Wr, br, X);
    k_scan<<<1, 256, 0, stream>>>(X, Ui, Uf, Ur, Wout, bout, out);
}

// Round 22
// 68.413 us; speedup vs baseline: 1.3784x; 1.0518x over previous
//
#include <hip/hip_runtime.h>
#include <cmath>

#define S_   128
#define W_   64
#define D_   200
#define H_   50
#define OUT_ 5

// ---------------------------------------------------------------------------
// Kernel 1: one block per sentence (conv+pool commuted into the projection).
// ---------------------------------------------------------------------------
__global__ __launch_bounds__(256) void k_sent(
    const int* __restrict__ doc, const float* __restrict__ emb,
    const float* __restrict__ w_word, const float* __restrict__ b_word,
    const float* __restrict__ cw1, const float* __restrict__ cb1,
    const float* __restrict__ cw2, const float* __restrict__ cb2,
    const float* __restrict__ cw3, const float* __restrict__ cb3,
    const float* __restrict__ Wi, const float* __restrict__ bi,
    const float* __restrict__ Wf, const float* __restrict__ bf,
    const float* __restrict__ Wr, const float* __restrict__ br,
    float* __restrict__ Xout)   // [3][S_][H_]
{
    const int s   = blockIdx.x;
    const int tid = threadIdx.x;

    __shared__ int   drow[W_];
    __shared__ float vec[5][D_];     // full sum, E0, E1, E62, E63
    __shared__ float q[5][H_];       // w_word @ each of the above
    __shared__ float m[6][H_ + 2];   // the 6 window means
    __shared__ float reps_sh[H_];

    if (tid < W_) drow[tid] = doc[s * W_ + tid];
    __syncthreads();

    if (tid < D_) {
        const int d = tid;
        float acc = 0.f;
        for (int u = 0; u < W_; ++u)
            acc += emb[(size_t)drow[u] * D_ + d];
        vec[0][d] = acc;
        vec[1][d] = emb[(size_t)drow[0]      * D_ + d];
        vec[2][d] = emb[(size_t)drow[1]      * D_ + d];
        vec[3][d] = emb[(size_t)drow[W_ - 2] * D_ + d];
        vec[4][d] = emb[(size_t)drow[W_ - 1] * D_ + d];
    }
    __syncthreads();

    if (tid < 5 * H_) {
        const int v = tid / H_, h = tid % H_;
        const float* wr = w_word + h * D_;
        float acc = 0.f;
        for (int d = 0; d < D_; ++d) acc += wr[d] * vec[v][d];
        q[v][h] = acc;
    }
    __syncthreads();

    if (tid < H_) {
        const int h = tid;
        const float qf = q[0][h], q0 = q[1][h], q1 = q[2][h],
                    q62 = q[3][h], q63 = q[4][h];
        const float bw = b_word[h];
        m[0][h] = qf               * (1.f / 64.f) + bw;
        m[1][h] = (qf - q63)       * (1.f / 63.f) + bw;
        m[2][h] = (qf - q0)        * (1.f / 63.f) + bw;
        m[3][h] = (qf - q62 - q63) * (1.f / 62.f) + bw;
        m[4][h] = (qf - q0  - q63) * (1.f / 62.f) + bw;
        m[5][h] = (qf - q0  - q1)  * (1.f / 62.f) + bw;
    }
    __syncthreads();

    if (tid < H_) {
        const int o = tid;
        float a1 = cb1[o], a2 = cb2[o], a3 = cb3[o];
        for (int i = 0; i < H_; ++i) {
            a1 += cw1[o * H_ + i] * m[0][i];
            const float* c2 = cw2 + (o * H_ + i) * 2;
            a2 += c2[0] * m[1][i] + c2[1] * m[2][i];
            const float* c3 = cw3 + (o * H_ + i) * 3;
            a3 += c3[0] * m[3][i] + c3[1] * m[4][i] + c3[2] * m[5][i];
        }
        reps_sh[o] = (tanhf(a1) + tanhf(a2) + tanhf(a3)) * (1.f / 3.f);
    }
    __syncthreads();

    if (tid < 3 * H_) {
        const int g = tid / H_, o = tid % H_;
        const float* Wg = (g == 0) ? Wi : (g == 1) ? Wf : Wr;
        const float* bg = (g == 0) ? bi : (g == 1) ? bf : br;
        float acc = bg[o];
        for (int j = 0; j < H_; ++j) acc += Wg[o * H_ + j] * reps_sh[j];
        Xout[(g * S_ + s) * H_ + o] = acc;
    }
}

// ---------------------------------------------------------------------------
// Kernel 2 (v11): v10 (4-wave column split + fast gates + padded exchange,
// 55.7us) with the barrier de-fanged. __syncthreads() emits
// `s_waitcnt vmcnt(0) ... lgkmcnt(0); s_barrier` -- the vmcnt(0) forces the
// 3 per-step X prefetch loads (issued at loop top, needed only NEXT step)
// to complete before every barrier, turning the prefetch into a ~150-250cyc
// serial stall each step (the exact barrier-drain pathology the GEMM ladder
// measured). Replace with: asm lgkmcnt(0) (drain only the ds_writes other
// waves must see) + s_barrier + sched_barrier(0) (rule #18 fence -- keeps
// the compiler from hoisting post-barrier LDS reads above the barrier).
// X loads now stay in flight across the barrier.
// ---------------------------------------------------------------------------
#define JW 13   // columns per wave (4*13 = 52 >= 50; tail guarded)

__device__ __forceinline__ float rcp_fast(float x) {
    return __builtin_amdgcn_rcpf(x);
}

__device__ __forceinline__ float tanh_fast(float x) {
    float e = __expf(2.f * x);
    return (e - 1.f) * rcp_fast(e + 1.f);
}

__device__ __forceinline__ float sigmoid_fast(float x) {
    return rcp_fast(1.f + __expf(-x));
}

__device__ __forceinline__ float bcast(float v, int lane) {
    return __int_as_float(__builtin_amdgcn_readlane(__float_as_int(v), lane));
}

// lgkmcnt-only barrier: ds-writes drained, vmcnt (X prefetch) stays in flight
__device__ __forceinline__ void barrier_lds_only() {
    asm volatile("s_waitcnt lgkmcnt(0)" ::: "memory");
    __builtin_amdgcn_s_barrier();
    __builtin_amdgcn_sched_barrier(0);
}

__global__ __launch_bounds__(256, 1) void k_scan(
    const float* __restrict__ X,   // [3][S_][H_]
    const float* __restrict__ Ui, const float* __restrict__ Uf,
    const float* __restrict__ Ur,
    const float* __restrict__ Wout, const float* __restrict__ bout,
    float* __restrict__ out)
{
    const int tid = threadIdx.x;
    const int w   = tid >> 6;                 // wave: 0..3
    const int o   = tid & 63;
    const int ro  = (o < H_) ? o : (H_ - 1);  // clamped row, all lanes in-bounds
    const int jlo = w * JW;                   // this wave's column window

    // part[parity][gate][o][wave(+pad)]: stride 5 -> conflict-free (v8: 0)
    __shared__ float part[2][3][64][5];

    float ua[JW], ub[JW], uc[JW];
    {
        const float* Uir = Ui + ro * H_;
        const float* Ufr = Uf + ro * H_;
        const float* Urr = Ur + ro * H_;
        #pragma unroll
        for (int jj = 0; jj < JW; ++jj) {
            const int j = jlo + jj;
            const bool ok = (j < H_);
            ua[jj] = ok ? Uir[j] : 0.f;
            ub[jj] = ok ? Ufr[j] : 0.f;
            uc[jj] = ok ? Urr[j] : 0.f;
        }
    }

    float h  = 0.f;                            // lane o holds h[o] (all waves)
    float xi = X[(0 * S_ + 0) * H_ + ro];
    float xf = X[(1 * S_ + 0) * H_ + ro];
    float xr = X[(2 * S_ + 0) * H_ + ro];

    int p = 0;
    for (int t = 0; t < S_; ++t) {
        const int tn = (t + 1 < S_) ? (t + 1) : (S_ - 1);   // clamped prefetch
        float nxi = X[(0 * S_ + tn) * H_ + ro];
        float nxf = X[(1 * S_ + tn) * H_ + ro];
        float nxr = X[(2 * S_ + tn) * H_ + ro];

        // partial dots over this wave's column window
        float pi = 0.f, pf = 0.f, pr = 0.f;
        #pragma unroll
        for (int jj = 0; jj < JW; ++jj) {
            const int j  = jlo + jj;
            const int jl = (j < H_) ? j : (H_ - 1);  // wave-uniform SGPR index
            float hj = bcast(h, jl);                 // garbage*0 stays finite
            pi += ua[jj] * hj;
            pf += ub[jj] * hj;
            pr += uc[jj] * hj;
        }
        part[p][0][o][w] = pi;
        part[p][1][o][w] = pf;
        part[p][2][o][w] = pr;
        barrier_lds_only();                    // ds_writes drained; X in flight

        float ai = xi + (part[p][0][o][0] + part[p][0][o][1])
                      + (part[p][0][o][2] + part[p][0][o][3]);
        float af = xf + (part[p][1][o][0] + part[p][1][o][1])
                      + (part[p][1][o][2] + part[p][1][o][3]);
        float ar = xr + (part[p][2][o][0] + part[p][2][o][1])
                      + (part[p][2][o][2] + part[p][2][o][3]);

        float gi = sigmoid_fast(ai);
        float gf = sigmoid_fast(af);
        float gg = tanh_fast(ar);
        h = tanh_fast(gi * gg + gf * h);       // identical in all waves

        xi = nxi; xf = nxf; xr = nxr;
        p ^= 1;                                // double buffer: no 2nd barrier
    }

    // output head (all waves compute identically; tid 0 stores)
    float logit = (o < OUT_) ? bout[o] : 0.f;
    const float* wrow = Wout + ((o < OUT_) ? o : 0) * H_;
    #pragma unroll
    for (int j = 0; j < H_; ++j) {
        float hj = bcast(h, j);
        logit += wrow[j] * hj;
    }
    float l0 = bcast(logit, 0), l1 = bcast(logit, 1), l2 = bcast(logit, 2),
          l3 = bcast(logit, 3), l4 = bcast(logit, 4);
    float mx = fmaxf(fmaxf(fmaxf(l0, l1), fmaxf(l2, l3)), l4);
    float e0 = __expf(l0 - mx), e1 = __expf(l1 - mx), e2 = __expf(l2 - mx),
          e3 = __expf(l3 - mx), e4 = __expf(l4 - mx);
    float s = e0 + e1 + e2 + e3 + e4;
    if (tid == 0) {
        float rs = 1.f / s;   // one IEEE div in the epilogue is fine
        out[0] = e0 * rs; out[1] = e1 * rs; out[2] = e2 * rs;
        out[3] = e3 * rs; out[4] = e4 * rs;
    }
}

extern "C" void kernel_launch(void* const* d_in, const int* in_sizes, int n_in,
                              void* d_out, int out_size, void* d_ws, size_t ws_size,
                              hipStream_t stream) {
    (void)in_sizes; (void)n_in; (void)out_size; (void)ws_size;

    const int*   doc    = (const int*)  d_in[0];
    const float* emb    = (const float*)d_in[1];
    const float* w_word = (const float*)d_in[2];
    const float* b_word = (const float*)d_in[3];
    const float* cw1    = (const float*)d_in[4];
    const float* cb1    = (const float*)d_in[5];
    const float* cw2    = (const float*)d_in[6];
    const float* cb2    = (const float*)d_in[7];
    const float* cw3    = (const float*)d_in[8];
    const float* cb3    = (const float*)d_in[9];
    const float* Wi     = (const float*)d_in[10];
    const float* Ui     = (const float*)d_in[11];
    const float* bi     = (const float*)d_in[12];
    const float* Wf     = (const float*)d_in[13];
    const float* Uf     = (const float*)d_in[14];
    const float* bf     = (const float*)d_in[15];
    const float* Wr     = (const float*)d_in[16];
    const float* Ur     = (const float*)d_in[17];
    const float* br     = (const float*)d_in[18];
    const float* Wout   = (const float*)d_in[19];
    const float* bout   = (const float*)d_in[20];

    float* X = (float*)d_ws;                 // [3][S_][H_] f32 = 76.8 KB
    float* out = (float*)d_out;

    k_sent<<<S_, 256, 0, stream>>>(doc, emb, w_word, b_word,
                                   cw1, cb1, cw2, cb2, cw3, cb3,
                                   Wi, bi, Wf, bf, Wr, br, X);
    k_scan<<<1, 256, 0, stream>>>(X, Ui, Uf, Ur, Wout, bout, out);
}

// Round 23
// 68.204 us; speedup vs baseline: 1.3827x; 1.0031x over previous
//
#include <hip/hip_runtime.h>
#include <cmath>

#define S_   128
#define W_   64
#define D_   200
#define H_   50
#define OUT_ 5

// ---------------------------------------------------------------------------
// Kernel 1: one block per sentence (conv+pool commuted into the projection).
// ---------------------------------------------------------------------------
__global__ __launch_bounds__(256) void k_sent(
    const int* __restrict__ doc, const float* __restrict__ emb,
    const float* __restrict__ w_word, const float* __restrict__ b_word,
    const float* __restrict__ cw1, const float* __restrict__ cb1,
    const float* __restrict__ cw2, const float* __restrict__ cb2,
    const float* __restrict__ cw3, const float* __restrict__ cb3,
    const float* __restrict__ Wi, const float* __restrict__ bi,
    const float* __restrict__ Wf, const float* __restrict__ bf,
    const float* __restrict__ Wr, const float* __restrict__ br,
    float* __restrict__ Xout)   // [3][S_][H_]
{
    const int s   = blockIdx.x;
    const int tid = threadIdx.x;

    __shared__ int   drow[W_];
    __shared__ float vec[5][D_];     // full sum, E0, E1, E62, E63
    __shared__ float q[5][H_];       // w_word @ each of the above
    __shared__ float m[6][H_ + 2];   // the 6 window means
    __shared__ float reps_sh[H_];

    if (tid < W_) drow[tid] = doc[s * W_ + tid];
    __syncthreads();

    if (tid < D_) {
        const int d = tid;
        float acc = 0.f;
        for (int u = 0; u < W_; ++u)
            acc += emb[(size_t)drow[u] * D_ + d];
        vec[0][d] = acc;
        vec[1][d] = emb[(size_t)drow[0]      * D_ + d];
        vec[2][d] = emb[(size_t)drow[1]      * D_ + d];
        vec[3][d] = emb[(size_t)drow[W_ - 2] * D_ + d];
        vec[4][d] = emb[(size_t)drow[W_ - 1] * D_ + d];
    }
    __syncthreads();

    if (tid < 5 * H_) {
        const int v = tid / H_, h = tid % H_;
        const float* wr = w_word + h * D_;
        float acc = 0.f;
        for (int d = 0; d < D_; ++d) acc += wr[d] * vec[v][d];
        q[v][h] = acc;
    }
    __syncthreads();

    if (tid < H_) {
        const int h = tid;
        const float qf = q[0][h], q0 = q[1][h], q1 = q[2][h],
                    q62 = q[3][h], q63 = q[4][h];
        const float bw = b_word[h];
        m[0][h] = qf               * (1.f / 64.f) + bw;
        m[1][h] = (qf - q63)       * (1.f / 63.f) + bw;
        m[2][h] = (qf - q0)        * (1.f / 63.f) + bw;
        m[3][h] = (qf - q62 - q63) * (1.f / 62.f) + bw;
        m[4][h] = (qf - q0  - q63) * (1.f / 62.f) + bw;
        m[5][h] = (qf - q0  - q1)  * (1.f / 62.f) + bw;
    }
    __syncthreads();

    if (tid < H_) {
        const int o = tid;
        float a1 = cb1[o], a2 = cb2[o], a3 = cb3[o];
        for (int i = 0; i < H_; ++i) {
            a1 += cw1[o * H_ + i] * m[0][i];
            const float* c2 = cw2 + (o * H_ + i) * 2;
            a2 += c2[0] * m[1][i] + c2[1] * m[2][i];
            const float* c3 = cw3 + (o * H_ + i) * 3;
            a3 += c3[0] * m[3][i] + c3[1] * m[4][i] + c3[2] * m[5][i];
        }
        reps_sh[o] = (tanhf(a1) + tanhf(a2) + tanhf(a3)) * (1.f / 3.f);
    }
    __syncthreads();

    if (tid < 3 * H_) {
        const int g = tid / H_, o = tid % H_;
        const float* Wg = (g == 0) ? Wi : (g == 1) ? Wf : Wr;
        const float* bg = (g == 0) ? bi : (g == 1) ? bf : br;
        float acc = bg[o];
        for (int j = 0; j < H_; ++j) acc += Wg[o * H_ + j] * reps_sh[j];
        Xout[(g * S_ + s) * H_ + o] = acc;
    }
}

// ---------------------------------------------------------------------------
// Kernel 2 (v12): v11 (4-wave split + fast gates + padded exchange +
// lgkmcnt-only barrier, 52.4us) with chain-ILP in the dots. Measured model:
// per-step ~= chain-instrs x ~6cyc (dependent VALU, no TLP: all 4 waves run
// the same lockstep chain) + ~300cyc LDS round-trip. Fix the ~6cyc/instr:
// (1) hoist all 13 readlanes into an independent batch (only depend on h),
// (2) two accumulators per gate -> chain depth 13->7, six concurrent FMA
// chains -> dep stalls overlap.
// ---------------------------------------------------------------------------
#define JW 13   // columns per wave (4*13 = 52 >= 50; tail guarded)

__device__ __forceinline__ float rcp_fast(float x) {
    return __builtin_amdgcn_rcpf(x);
}

__device__ __forceinline__ float tanh_fast(float x) {
    float e = __expf(2.f * x);
    return (e - 1.f) * rcp_fast(e + 1.f);
}

__device__ __forceinline__ float sigmoid_fast(float x) {
    return rcp_fast(1.f + __expf(-x));
}

__device__ __forceinline__ float bcast(float v, int lane) {
    return __int_as_float(__builtin_amdgcn_readlane(__float_as_int(v), lane));
}

// lgkmcnt-only barrier: ds-writes drained, vmcnt (X prefetch) stays in flight
__device__ __forceinline__ void barrier_lds_only() {
    asm volatile("s_waitcnt lgkmcnt(0)" ::: "memory");
    __builtin_amdgcn_s_barrier();
    __builtin_amdgcn_sched_barrier(0);
}

__global__ __launch_bounds__(256, 1) void k_scan(
    const float* __restrict__ X,   // [3][S_][H_]
    const float* __restrict__ Ui, const float* __restrict__ Uf,
    const float* __restrict__ Ur,
    const float* __restrict__ Wout, const float* __restrict__ bout,
    float* __restrict__ out)
{
    const int tid = threadIdx.x;
    const int w   = tid >> 6;                 // wave: 0..3
    const int o   = tid & 63;
    const int ro  = (o < H_) ? o : (H_ - 1);  // clamped row, all lanes in-bounds
    const int jlo = w * JW;                   // this wave's column window

    // part[parity][gate][o][wave(+pad)]: stride 5 -> conflict-free (v8: 0)
    __shared__ float part[2][3][64][5];

    float ua[JW], ub[JW], uc[JW];
    {
        const float* Uir = Ui + ro * H_;
        const float* Ufr = Uf + ro * H_;
        const float* Urr = Ur + ro * H_;
        #pragma unroll
        for (int jj = 0; jj < JW; ++jj) {
            const int j = jlo + jj;
            const bool ok = (j < H_);
            ua[jj] = ok ? Uir[j] : 0.f;
            ub[jj] = ok ? Ufr[j] : 0.f;
            uc[jj] = ok ? Urr[j] : 0.f;
        }
    }

    float h  = 0.f;                            // lane o holds h[o] (all waves)
    float xi = X[(0 * S_ + 0) * H_ + ro];
    float xf = X[(1 * S_ + 0) * H_ + ro];
    float xr = X[(2 * S_ + 0) * H_ + ro];

    int p = 0;
    for (int t = 0; t < S_; ++t) {
        const int tn = (t + 1 < S_) ? (t + 1) : (S_ - 1);   // clamped prefetch
        float nxi = X[(0 * S_ + tn) * H_ + ro];
        float nxf = X[(1 * S_ + tn) * H_ + ro];
        float nxr = X[(2 * S_ + tn) * H_ + ro];

        // batch all broadcasts first (independent; only depend on h)
        float hj[JW];
        #pragma unroll
        for (int jj = 0; jj < JW; ++jj) {
            const int j  = jlo + jj;
            const int jl = (j < H_) ? j : (H_ - 1);  // wave-uniform SGPR index
            hj[jj] = bcast(h, jl);
        }

        // six concurrent FMA chains: 2 accumulators per gate, depth 7
        float pi0 = 0.f, pi1 = 0.f, pf0 = 0.f, pf1 = 0.f,
              pr0 = 0.f, pr1 = 0.f;
        #pragma unroll
        for (int jj = 0; jj + 1 < JW; jj += 2) {
            pi0 += ua[jj]     * hj[jj];
            pf0 += ub[jj]     * hj[jj];
            pr0 += uc[jj]     * hj[jj];
            pi1 += ua[jj + 1] * hj[jj + 1];
            pf1 += ub[jj + 1] * hj[jj + 1];
            pr1 += uc[jj + 1] * hj[jj + 1];
        }
        pi0 += ua[JW - 1] * hj[JW - 1];        // JW odd: tail on chain 0
        pf0 += ub[JW - 1] * hj[JW - 1];
        pr0 += uc[JW - 1] * hj[JW - 1];

        part[p][0][o][w] = pi0 + pi1;
        part[p][1][o][w] = pf0 + pf1;
        part[p][2][o][w] = pr0 + pr1;
        barrier_lds_only();                    // ds_writes drained; X in flight

        float ai = xi + (part[p][0][o][0] + part[p][0][o][1])
                      + (part[p][0][o][2] + part[p][0][o][3]);
        float af = xf + (part[p][1][o][0] + part[p][1][o][1])
                      + (part[p][1][o][2] + part[p][1][o][3]);
        float ar = xr + (part[p][2][o][0] + part[p][2][o][1])
                      + (part[p][2][o][2] + part[p][2][o][3]);

        float gi = sigmoid_fast(ai);
        float gf = sigmoid_fast(af);
        float gg = tanh_fast(ar);
        h = tanh_fast(gi * gg + gf * h);       // identical in all waves

        xi = nxi; xf = nxf; xr = nxr;
        p ^= 1;                                // double buffer: no 2nd barrier
    }

    // output head (all waves compute identically; tid 0 stores)
    float logit = (o < OUT_) ? bout[o] : 0.f;
    const float* wrow = Wout + ((o < OUT_) ? o : 0) * H_;
    #pragma unroll
    for (int j = 0; j < H_; ++j) {
        float hj = bcast(h, j);
        logit += wrow[j] * hj;
    }
    float l0 = bcast(logit, 0), l1 = bcast(logit, 1), l2 = bcast(logit, 2),
          l3 = bcast(logit, 3), l4 = bcast(logit, 4);
    float mx = fmaxf(fmaxf(fmaxf(l0, l1), fmaxf(l2, l3)), l4);
    float e0 = __expf(l0 - mx), e1 = __expf(l1 - mx), e2 = __expf(l2 - mx),
          e3 = __expf(l3 - mx), e4 = __expf(l4 - mx);
    float s = e0 + e1 + e2 + e3 + e4;
    if (tid == 0) {
        float rs = 1.f / s;   // one IEEE div in the epilogue is fine
        out[0] = e0 * rs; out[1] = e1 * rs; out[2] = e2 * rs;
        out[3] = e3 * rs; out[4] = e4 * rs;
    }
}

extern "C" void kernel_launch(void* const* d_in, const int* in_sizes, int n_in,
                              void* d_out, int out_size, void* d_ws, size_t ws_size,
                              hipStream_t stream) {
    (void)in_sizes; (void)n_in; (void)out_size; (void)ws_size;

    const int*   doc    = (const int*)  d_in[0];
    const float* emb    = (const float*)d_in[1];
    const float* w_word = (const float*)d_in[2];
    const float* b_word = (const float*)d_in[3];
    const float* cw1    = (const float*)d_in[4];
    const float* cb1    = (const float*)d_in[5];
    const float* cw2    = (const float*)d_in[6];
    const float* cb2    = (const float*)d_in[7];
    const float* cw3    = (const float*)d_in[8];
    const float* cb3    = (const float*)d_in[9];
    const float* Wi     = (const float*)d_in[10];
    const float* Ui     = (const float*)d_in[11];
    const float* bi     = (const float*)d_in[12];
    const float* Wf     = (const float*)d_in[13];
    const float* Uf     = (const float*)d_in[14];
    const float* bf     = (const float*)d_in[15];
    const float* Wr     = (const float*)d_in[16];
    const float* Ur     = (const float*)d_in[17];
    const float* br     = (const float*)d_in[18];
    const float* Wout   = (const float*)d_in[19];
    const float* bout   = (const float*)d_in[20];

    float* X = (float*)d_ws;                 // [3][S_][H_] f32 = 76.8 KB
    float* out = (float*)d_out;

    k_sent<<<S_, 256, 0, stream>>>(doc, emb, w_word, b_word,
                                   cw1, cb1, cw2, cb2, cw3, cb3,
                                   Wi, bi, Wf, bf, Wr, br, X);
    k_scan<<<1, 256, 0, stream>>>(X, Ui, Uf, Ur, Wout, bout, out);
}